// Round 5
// baseline (288.638 us; speedup 1.0000x reference)
//
#include <hip/hip_runtime.h>

// CRF forward partition, MI355X. B=1024, L=512, T=52.
//
// p-space recurrence: p_new[j] = exp(f[t,j]) * sum_i E[i][j]*p[i],
// E = exp(transitions), constant. One wave per batch; lane j owns tag j;
// p broadcast wave-uniform via v_readlane (ps -> SGPRs).
//
// R5 vs R2: the matvec fmacs are emitted via inline asm
//   v_fmac_f32 acc, s(ps[i]), v(E[i])
// R2-R4 evidence: compiler parks E[52] in AGPRs (VGPR_Count=36/52) and
// pays a v_accvgpr_read per fmac because fmaf(SGPR, AGPR, VGPR) has two
// non-VGPR sources. The asm constraint "v" on E makes AGPR placement cost
// explicit copies, forcing arch-VGPR residency; "s" on ps keeps the legal
// VOP2 form (src0=SGPR, vsrc1=VGPR).

#define TT 52   // TAG_SIZE
#define LL 512  // sequence length
#define NS 4    // steps per group; normalize once per group

__device__ __forceinline__ float rl(float x, int lane) {
    return __int_as_float(__builtin_amdgcn_readlane(__float_as_int(x), lane));
}

__device__ __forceinline__ void fmac_sv(float& acc, float s, float v) {
    asm("v_fmac_f32 %0, %1, %2" : "+v"(acc) : "s"(s), "v"(v));
}

__global__ void __launch_bounds__(64, 1) crf_fwd(
    const float* __restrict__ feats,   // (B, L, T)
    const int*   __restrict__ mask,    // (B, L)
    const float* __restrict__ trans,   // (T, T)
    float*       __restrict__ out)     // scalar accumulator (pre-zeroed)
{
    const int b = blockIdx.x;
    const int j = threadIdx.x;          // lane = destination tag
    const bool act = (j < TT);
    const int jc = act ? j : 0;         // clamped index for safe loads

    const float* fb = feats + (size_t)b * LL * TT;
    const int*   mb = mask  + (size_t)b * LL;

    // Per-lane transition column: E[i] = exp(trans[i][j]).
    // -1000 entries (START col / END row) become exact 0.
    float E[TT];
#pragma unroll
    for (int i = 0; i < TT; ++i) {
        float e = __expf(trans[i * TT + jc]);
        E[i] = act ? e : 0.0f;
    }

    // t=0 init: part0[j] = feats[b,0,j] + trans[START][j]; normalize by lane 0.
    float part0 = act ? (fb[j] + trans[(TT - 2) * TT + j]) : -1.0e30f;
    float shift = rl(part0, 0);
    float pv = act ? __expf(part0 - shift) : 0.0f;   // lane j holds p[j]

    // Wave-uniform copy of p (targets SGPRs via readlane).
    float ps[TT];
#pragma unroll
    for (int i = 0; i < TT; ++i) ps[i] = rl(pv, i);

    // Prefetch ring (clamped indices => no guard branches, always in-bounds).
    float fpre[NS];
    int   mc[NS];
#pragma unroll
    for (int u = 0; u < NS; ++u) {
        int t = 1 + u;                  // all < LL
        fpre[u] = fb[t * TT + jc];
        mc[u]   = mb[t];
    }

    // Main loop: 127 branch-free groups covering t = 1 .. 508.
    for (int t0 = 1; t0 < LL - NS + 1; t0 += NS) {
        // issue next group's loads first (~4 steps of latency slack)
        float fnx[NS];
        int   mn[NS];
#pragma unroll
        for (int u = 0; u < NS; ++u) {
            int tn = t0 + NS + u;
            int tcl = tn < LL ? tn : (LL - 1);   // clamp (tail overrun harmless)
            fnx[u] = fb[tcl * TT + jc];
            mn[u]  = mb[tcl];
        }

#pragma unroll
        for (int u = 0; u < NS; ++u) {
            float ef = __expf(fpre[u]);
            // s_j = sum_i E[i][j] * p[i]  (4 independent FMA chains)
            float a0 = 0.f, a1 = 0.f, a2 = 0.f, a3 = 0.f;
#pragma unroll
            for (int i = 0; i < TT; i += 4) {
                fmac_sv(a0, ps[i + 0], E[i + 0]);
                fmac_sv(a1, ps[i + 1], E[i + 1]);
                fmac_sv(a2, ps[i + 2], E[i + 2]);
                fmac_sv(a3, ps[i + 3], E[i + 3]);
            }
            float pn = ((a0 + a1) + (a2 + a3)) * ef;
            pv = (mc[u] > 0) ? pn : pv;          // branchless mask select
            if (u == NS - 1) {
                // normalize once per group by lane 0 (>0 always); track shift
                float c = rl(pv, 0);
                shift += __logf(c);
                pv *= __builtin_amdgcn_rcpf(c);
            }
#pragma unroll
            for (int i = 0; i < TT; ++i) ps[i] = rl(pv, i);
        }
#pragma unroll
        for (int u = 0; u < NS; ++u) { fpre[u] = fnx[u]; mc[u] = mn[u]; }
    }

    // Tail: t = 509, 510, 511 (3 steps, data already in fpre[0..2]).
#pragma unroll
    for (int u = 0; u < 3; ++u) {
        float ef = __expf(fpre[u]);
        float a0 = 0.f, a1 = 0.f, a2 = 0.f, a3 = 0.f;
#pragma unroll
        for (int i = 0; i < TT; i += 4) {
            fmac_sv(a0, ps[i + 0], E[i + 0]);
            fmac_sv(a1, ps[i + 1], E[i + 1]);
            fmac_sv(a2, ps[i + 2], E[i + 2]);
            fmac_sv(a3, ps[i + 3], E[i + 3]);
        }
        float pn = ((a0 + a1) + (a2 + a3)) * ef;
        pv = (mc[u] > 0) ? pn : pv;
#pragma unroll
        for (int i = 0; i < TT; ++i) ps[i] = rl(pv, i);
    }

    // Final: log(sum_i exp(trans[i][END]) * p[i]) + shift
    float eend = __expf(trans[jc * TT + (TT - 1)]);
    float val = act ? (eend * pv) : 0.0f;
#pragma unroll
    for (int o = 32; o >= 1; o >>= 1)
        val += __shfl_xor(val, o, 64);
    if (j == 0) atomicAdd(out, __logf(val) + shift);
}

extern "C" void kernel_launch(void* const* d_in, const int* in_sizes, int n_in,
                              void* d_out, int out_size, void* d_ws, size_t ws_size,
                              hipStream_t stream) {
    const float* feats = (const float*)d_in[0];
    const int*   mask  = (const int*)d_in[1];
    const float* trans = (const float*)d_in[2];
    float* out = (float*)d_out;

    const int B = in_sizes[1] / LL;   // mask is (B, L)

    hipMemsetAsync(d_out, 0, sizeof(float), stream);
    crf_fwd<<<B, 64, 0, stream>>>(feats, mask, trans, out);
}

// Round 6
// 252.366 us; speedup vs baseline: 1.1437x; 1.1437x over previous
//
#include <hip/hip_runtime.h>

// CRF forward partition, MI355X. B=1024, L=512, T=52.
//
// p-space recurrence: p_new[j] = exp(f[t,j]) * sum_i E[i][j]*p[i],
// E = exp(transitions), constant. One wave per batch; lane j owns tag j;
// p broadcast wave-uniform via v_readlane -> SGPRs (ps).
//
// R6 vs R2: enforce hazard-free block scheduling.
//  - R5 evidence: E-in-AGPR is FREE (fmac reads AGPR directly, unified RF);
//    R2's ~300 idle cyc/step modeled as VALU-writes-SGPR -> VALU-reads-SGPR
//    wait states from the scheduler interleaving readlane_i with fmac_i.
//  - Fix: sched_barrier(0) fences so all 52 readlanes issue as one block,
//    then all 52 fmacs => every SGPR read is >=52 insts after its write.
//  - waves_per_eu(1,1) (R3 only pinned the min), normalize every 8 steps.

#define TT 52   // TAG_SIZE
#define LL 512  // sequence length
#define NS 8    // steps per group; normalize once per group

__device__ __forceinline__ float rl(float x, int lane) {
    return __int_as_float(__builtin_amdgcn_readlane(__float_as_int(x), lane));
}

__global__ void __launch_bounds__(64)
__attribute__((amdgpu_waves_per_eu(1, 1)))
crf_fwd(
    const float* __restrict__ feats,   // (B, L, T)
    const int*   __restrict__ mask,    // (B, L)
    const float* __restrict__ trans,   // (T, T)
    float*       __restrict__ out)     // scalar accumulator (pre-zeroed)
{
    const int b = blockIdx.x;
    const int j = threadIdx.x;          // lane = destination tag
    const bool act = (j < TT);
    const int jc = act ? j : 0;         // clamped index for safe loads

    const float* fb = feats + (size_t)b * LL * TT;
    const int*   mb = mask  + (size_t)b * LL;

    // Per-lane transition column: E[i] = exp(trans[i][j]).
    // -1000 entries (START col / END row) become exact 0.
    float E[TT];
#pragma unroll
    for (int i = 0; i < TT; ++i) {
        float e = __expf(trans[i * TT + jc]);
        E[i] = act ? e : 0.0f;
    }

    // t=0 init: part0[j] = feats[b,0,j] + trans[START][j]; normalize by lane 0.
    float part0 = act ? (fb[j] + trans[(TT - 2) * TT + j]) : -1.0e30f;
    float shift = rl(part0, 0);
    float pv = act ? __expf(part0 - shift) : 0.0f;   // lane j holds p[j]

    // Wave-uniform copy of p (targets SGPRs via readlane).
    float ps[TT];
#pragma unroll
    for (int i = 0; i < TT; ++i) ps[i] = rl(pv, i);

    // Prefetch ring (always in-bounds; no guard branches).
    float fpre[NS];
    int   mc[NS];
#pragma unroll
    for (int u = 0; u < NS; ++u) {
        int t = 1 + u;                  // all < LL
        fpre[u] = fb[t * TT + jc];
        mc[u]   = mb[t];
    }

    // Main loop: 63 groups of 8 covering t = 1 .. 504; tail 505..511.
    for (int t0 = 1; t0 + NS <= LL; t0 += NS) {
        // next group's loads first (8 steps of latency slack)
        float fnx[NS];
        int   mn[NS];
#pragma unroll
        for (int u = 0; u < NS; ++u) {
            int tn = t0 + NS + u;
            int tcl = tn < LL ? tn : (LL - 1);   // clamp (tail overrun harmless)
            fnx[u] = fb[tcl * TT + jc];
            mn[u]  = mb[tcl];
        }

        // ef for the whole group upfront: independent of the recurrence chain
        float ef[NS];
#pragma unroll
        for (int u = 0; u < NS; ++u) ef[u] = __expf(fpre[u]);

#pragma unroll
        for (int u = 0; u < NS; ++u) {
            // s_j = sum_i E[i][j] * p[i]  (4 independent FMA chains)
            float a0 = 0.f, a1 = 0.f, a2 = 0.f, a3 = 0.f;
#pragma unroll
            for (int i = 0; i < TT; i += 4) {
                a0 = fmaf(ps[i + 0], E[i + 0], a0);
                a1 = fmaf(ps[i + 1], E[i + 1], a1);
                a2 = fmaf(ps[i + 2], E[i + 2], a2);
                a3 = fmaf(ps[i + 3], E[i + 3], a3);
            }
            float pn = ((a0 + a1) + (a2 + a3)) * ef[u];
            pv = (mc[u] > 0) ? pn : pv;          // branchless mask select
            if (u == NS - 1) {
                // normalize once per group by lane 0 (>0 always); track shift
                float c = rl(pv, 0);
                shift += __logf(c);
                pv *= __builtin_amdgcn_rcpf(c);
            }
            // --- hazard-free broadcast block: all readlanes back-to-back ---
            __builtin_amdgcn_sched_barrier(0);
#pragma unroll
            for (int i = 0; i < TT; ++i) ps[i] = rl(pv, i);
            __builtin_amdgcn_sched_barrier(0);
        }
#pragma unroll
        for (int u = 0; u < NS; ++u) { fpre[u] = fnx[u]; mc[u] = mn[u]; }
    }

    // Tail: t = 505..511 (7 steps, data already in fpre[0..6]).
#pragma unroll
    for (int u = 0; u < 7; ++u) {
        float ef = __expf(fpre[u]);
        float a0 = 0.f, a1 = 0.f, a2 = 0.f, a3 = 0.f;
#pragma unroll
        for (int i = 0; i < TT; i += 4) {
            a0 = fmaf(ps[i + 0], E[i + 0], a0);
            a1 = fmaf(ps[i + 1], E[i + 1], a1);
            a2 = fmaf(ps[i + 2], E[i + 2], a2);
            a3 = fmaf(ps[i + 3], E[i + 3], a3);
        }
        float pn = ((a0 + a1) + (a2 + a3)) * ef;
        pv = (mc[u] > 0) ? pn : pv;
        __builtin_amdgcn_sched_barrier(0);
#pragma unroll
        for (int i = 0; i < TT; ++i) ps[i] = rl(pv, i);
        __builtin_amdgcn_sched_barrier(0);
    }

    // Final: log(sum_i exp(trans[i][END]) * p[i]) + shift
    float eend = __expf(trans[jc * TT + (TT - 1)]);
    float val = act ? (eend * pv) : 0.0f;
#pragma unroll
    for (int o = 32; o >= 1; o >>= 1)
        val += __shfl_xor(val, o, 64);
    if (j == 0) atomicAdd(out, __logf(val) + shift);
}

extern "C" void kernel_launch(void* const* d_in, const int* in_sizes, int n_in,
                              void* d_out, int out_size, void* d_ws, size_t ws_size,
                              hipStream_t stream) {
    const float* feats = (const float*)d_in[0];
    const int*   mask  = (const int*)d_in[1];
    const float* trans = (const float*)d_in[2];
    float* out = (float*)d_out;

    const int B = in_sizes[1] / LL;   // mask is (B, L)

    hipMemsetAsync(d_out, 0, sizeof(float), stream);
    crf_fwd<<<B, 64, 0, stream>>>(feats, mask, trans, out);
}